// Round 1
// baseline (118823.779 us; speedup 1.0000x reference)
//
#include <hip/hip_runtime.h>
#include <math.h>

#define HID   256
#define GATES 1024   // 4*HID
#define BATCH 64
#define SEQ   2048

// ---------------------------------------------------------------------------
// GEMM: out[r][g] = sum_k A_row(r)[k] * W[g][k] + bias[g]
// A rows are chunk rows r = b*CH + t; A_row(r) = A + b*a_bstride + t*HID.
// W is [GATES, HID] row-major (w_ih layer slice). out is [M_chunk, GATES].
// 128x128 tile, BK=16, 256 threads, 8x8 micro-tile per thread.
// ---------------------------------------------------------------------------
#define BM 128
#define BN 128
#define BK 16
#define LDP 132   // padded LDS pitch (floats): keeps float4 alignment, kills conflicts

__global__ __launch_bounds__(256, 2)
void xg_gemm(const float* __restrict__ A, const float* __restrict__ W,
             const float* __restrict__ bias, float* __restrict__ out,
             int a_bstride, int ch_log2)
{
    __shared__ float As[BK][LDP];
    __shared__ float Ws[BK][LDP];

    const int tid   = threadIdx.x;
    const int m_blk = blockIdx.x * BM;
    const int n_blk = blockIdx.y * BN;

    // micro-fragment: rows {tm..tm+3, tm+64..tm+67}, cols {tn..tn+3, tn+64..tn+67}
    const int tn = (tid & 15) * 4;
    const int tm = (tid >> 4) * 4;

    float acc[8][8];
    #pragma unroll
    for (int i = 0; i < 8; ++i)
        #pragma unroll
        for (int j = 0; j < 8; ++j) acc[i][j] = 0.f;

    // staging loader mapping: each pass covers 64 rows x 16 k-cols
    const int lrow = tid >> 2;          // 0..63
    const int lkc  = (tid & 3) * 4;     // 0,4,8,12

    const int CHm1 = (1 << ch_log2) - 1;

    for (int k0 = 0; k0 < HID; k0 += BK) {
        // ---- stage A tile (transposed into As[k][m]) ----
        #pragma unroll
        for (int p = 0; p < 2; ++p) {
            int row = p * 64 + lrow;             // 0..127 (tile-local m)
            int r   = m_blk + row;               // chunk row
            int b   = r >> ch_log2;
            int t   = r & CHm1;
            const float4 a = *(const float4*)(A + (size_t)b * a_bstride +
                                              (size_t)t * HID + k0 + lkc);
            As[lkc + 0][row] = a.x;
            As[lkc + 1][row] = a.y;
            As[lkc + 2][row] = a.z;
            As[lkc + 3][row] = a.w;

            int g = n_blk + row;                 // gate row
            const float4 w = *(const float4*)(W + (size_t)g * HID + k0 + lkc);
            Ws[lkc + 0][row] = w.x;
            Ws[lkc + 1][row] = w.y;
            Ws[lkc + 2][row] = w.z;
            Ws[lkc + 3][row] = w.w;
        }
        __syncthreads();

        #pragma unroll
        for (int kk = 0; kk < BK; ++kk) {
            float4 a0 = *(const float4*)&As[kk][tm];
            float4 a1 = *(const float4*)&As[kk][tm + 64];
            float4 b0 = *(const float4*)&Ws[kk][tn];
            float4 b1 = *(const float4*)&Ws[kk][tn + 64];
            float av[8] = {a0.x, a0.y, a0.z, a0.w, a1.x, a1.y, a1.z, a1.w};
            float bv[8] = {b0.x, b0.y, b0.z, b0.w, b1.x, b1.y, b1.z, b1.w};
            #pragma unroll
            for (int i = 0; i < 8; ++i)
                #pragma unroll
                for (int j = 0; j < 8; ++j)
                    acc[i][j] += av[i] * bv[j];
        }
        __syncthreads();
    }

    const float4 bias0 = *(const float4*)&bias[n_blk + tn];
    const float4 bias1 = *(const float4*)&bias[n_blk + tn + 64];
    #pragma unroll
    for (int i = 0; i < 8; ++i) {
        int m  = (i < 4) ? (tm + i) : (tm + 60 + i);  // tm+64+(i-4)
        int gm = m_blk + m;
        float* op = out + (size_t)gm * GATES + n_blk;
        float4 v0 = {acc[i][0] + bias0.x, acc[i][1] + bias0.y,
                     acc[i][2] + bias0.z, acc[i][3] + bias0.w};
        float4 v1 = {acc[i][4] + bias1.x, acc[i][5] + bias1.y,
                     acc[i][6] + bias1.z, acc[i][7] + bias1.w};
        *(float4*)(op + tn)      = v0;
        *(float4*)(op + tn + 64) = v1;
    }
}

// ---------------------------------------------------------------------------
// Persistent recurrence over a time chunk: one workgroup per batch element.
// 1024 threads; thread g owns gate row g (dot of h[256] with w_hh row g).
// h, c live in LDS across the chunk. No cross-workgroup communication.
// ---------------------------------------------------------------------------
__device__ __forceinline__ float sigmoid_f(float x) {
    return 1.f / (1.f + __expf(-x));
}
__device__ __forceinline__ float tanh_f(float x) {
    // NaN-free fast tanh: 1 - 2/(1+e^{2x})
    return 1.f - 2.f / (1.f + __expf(2.f * x));
}

__global__ __launch_bounds__(1024)
void lstm_rec(const float* __restrict__ xg, const float* __restrict__ w_hh,
              const float* __restrict__ b_hh, float* __restrict__ h_state,
              float* __restrict__ c_state, float* __restrict__ h_out, int CH)
{
    __shared__ float h_s[HID];
    __shared__ float c_s[HID];
    __shared__ float g_s[GATES];

    const int b   = blockIdx.x;
    const int tid = threadIdx.x;

    if (tid < HID) {
        h_s[tid] = h_state[b * HID + tid];
        c_s[tid] = c_state[b * HID + tid];
    }
    __syncthreads();

    const float4* __restrict__ w4 = (const float4*)(w_hh + (size_t)tid * HID);
    const float   bh   = b_hh[tid];
    const float*  xg_b = xg + (size_t)b * CH * GATES + tid;

    for (int t = 0; t < CH; ++t) {
        const float4* h4 = (const float4*)h_s;
        float4 acc = {0.f, 0.f, 0.f, 0.f};
        #pragma unroll 8
        for (int j = 0; j < HID / 4; ++j) {
            float4 w = w4[j];
            float4 h = h4[j];   // broadcast: all lanes read same LDS address
            acc.x += w.x * h.x;
            acc.y += w.y * h.y;
            acc.z += w.z * h.z;
            acc.w += w.w * h.w;
        }
        g_s[tid] = xg_b[(size_t)t * GATES] + bh + ((acc.x + acc.y) + (acc.z + acc.w));
        __syncthreads();

        if (tid < HID) {
            float ig = sigmoid_f(g_s[tid]);
            float fg = sigmoid_f(g_s[tid + HID]);
            float gg = tanh_f(g_s[tid + 2 * HID]);
            float og = sigmoid_f(g_s[tid + 3 * HID]);
            float c  = fg * c_s[tid] + ig * gg;
            float h  = og * tanh_f(c);
            c_s[tid] = c;
            h_s[tid] = h;
            if (h_out) h_out[((size_t)b * CH + t) * HID + tid] = h;
        }
        __syncthreads();
    }

    if (tid < HID) {
        h_state[b * HID + tid] = h_s[tid];
        c_state[b * HID + tid] = c_s[tid];
    }
}

// ---------------------------------------------------------------------------
// Final linear: out[b] = dot(h2[b], w_lin) + b_lin. One wave per batch elem.
// ---------------------------------------------------------------------------
__global__ void final_linear(const float* __restrict__ h,
                             const float* __restrict__ w_lin,
                             const float* __restrict__ b_lin,
                             float* __restrict__ out)
{
    int b = blockIdx.x;
    int l = threadIdx.x;  // 0..63
    float p = 0.f;
    #pragma unroll
    for (int j = 0; j < 4; ++j) {
        int u = l + j * 64;
        p += h[b * HID + u] * w_lin[u];
    }
    #pragma unroll
    for (int off = 32; off > 0; off >>= 1) p += __shfl_down(p, off, 64);
    if (l == 0) out[b] = p + b_lin[0];
}

// ---------------------------------------------------------------------------
extern "C" void kernel_launch(void* const* d_in, const int* in_sizes, int n_in,
                              void* d_out, int out_size, void* d_ws, size_t ws_size,
                              hipStream_t stream)
{
    const float* input = (const float*)d_in[0];
    const float* w_ih  = (const float*)d_in[1];
    const float* w_hh  = (const float*)d_in[2];
    const float* b_ih  = (const float*)d_in[3];
    const float* b_hh  = (const float*)d_in[4];
    const float* w_lin = (const float*)d_in[5];
    const float* b_lin = (const float*)d_in[6];
    float* out = (float*)d_out;

    // time-chunk size chosen from ws_size (deterministic across calls)
    const size_t state_bytes = (size_t)4 * BATCH * HID * 4;  // h1,c1,h2,c2
    int CH = 128;
    while (CH > 16) {
        size_t need = state_bytes + (size_t)2 * BATCH * CH * GATES * 4
                                  + (size_t)BATCH * CH * HID * 4;
        if (need <= ws_size) break;
        CH >>= 1;
    }
    const int ch_log2 = __builtin_ctz((unsigned)CH);

    char* ws = (char*)d_ws;
    float* h1 = (float*)ws;
    float* c1 = h1 + BATCH * HID;
    float* h2 = c1 + BATCH * HID;
    float* c2 = h2 + BATCH * HID;
    float* xg1  = (float*)(ws + state_bytes);
    float* xg2  = xg1 + (size_t)BATCH * CH * GATES;
    float* h1ch = xg2 + (size_t)BATCH * CH * GATES;

    hipMemsetAsync(ws, 0, state_bytes, stream);  // zero h/c states

    const int NC = SEQ / CH;
    dim3 gblk(BATCH * CH / BM, GATES / BN);

    for (int c = 0; c < NC; ++c) {
        // layer 1 input GEMM for this chunk (reads strided rows of `input`)
        xg_gemm<<<gblk, 256, 0, stream>>>(input + (size_t)c * CH * HID, w_ih,
                                          b_ih, xg1, SEQ * HID, ch_log2);
        // layer 1 recurrence; emits h1 chunk
        lstm_rec<<<BATCH, 1024, 0, stream>>>(xg1, w_hh, b_hh, h1, c1, h1ch, CH);
        // layer 2 input GEMM from h1 chunk
        xg_gemm<<<gblk, 256, 0, stream>>>(h1ch, w_ih + GATES * HID,
                                          b_ih + GATES, xg2, CH * HID, ch_log2);
        // layer 2 recurrence; only carries state (no sequence output)
        lstm_rec<<<BATCH, 1024, 0, stream>>>(xg2, w_hh + GATES * HID,
                                             b_hh + GATES, h2, c2, nullptr, CH);
    }

    final_linear<<<BATCH, 64, 0, stream>>>(h2, w_lin, b_lin, out);
}